// Round 1
// 173.844 us; speedup vs baseline: 1.0323x; 1.0323x over previous
//
#include <hip/hip_runtime.h>
#include <hip/hip_bf16.h>
#include <cstdint>

#define B_ 8
#define S_ 2048
#define D_ 1024
#define U_ 1024
#define M_ (B_ * S_)   // 16384 rows

typedef __bf16 bf16x8 __attribute__((ext_vector_type(8)));
typedef float  f32x4  __attribute__((ext_vector_type(4)));

__device__ __forceinline__ uint16_t f2bf(float f) {
  uint32_t u = __builtin_bit_cast(uint32_t, f);
  u += 0x7fffu + ((u >> 16) & 1u);   // RNE
  return (uint16_t)(u >> 16);
}

// async 16B global->LDS copy (lane-contiguous LDS destination)
__device__ __forceinline__ void async_copy16(const void* g, void* l) {
  typedef const __attribute__((address_space(1))) uint8_t* gp_t;
  typedef __attribute__((address_space(3))) uint8_t* lp_t;
  __builtin_amdgcn_global_load_lds((gp_t)(uintptr_t)g,
                                   (lp_t)(uint32_t)(uintptr_t)l, 16, 0, 0);
}

// ---------------- kernel 1 (fused prep):
//   blocks [0, M_/4):      wave-per-row: x -> x_bf (bf16) + attn softmax (no barriers)
//   blocks [M_/4, +1024):  w [D][U] f32 -> wt [U][D] bf16 (LDS tile transpose)
__global__ __launch_bounds__(256) void k_prep(
    const float* __restrict__ x, const float* __restrict__ w_att,
    const float* __restrict__ b_att, const float* __restrict__ w,
    uint16_t* __restrict__ x_bf, float* __restrict__ attn,
    uint16_t* __restrict__ wt) {
  __shared__ float tile[32][33];     // used only by transpose blocks
  const int bid = blockIdx.x;
  if (bid < M_ / 4) {
    const int wave = threadIdx.x >> 6, lane = threadIdx.x & 63;
    const int row = bid * 4 + wave;
    const float4* xr = reinterpret_cast<const float4*>(x + (size_t)row * D_);
    const float4* wa4 = reinterpret_cast<const float4*>(w_att);
    float4 v[4];
#pragma unroll
    for (int i = 0; i < 4; i++) v[i] = xr[lane + 64 * i];   // 16 B/lane coalesced
    float4 p = {0.f, 0.f, 0.f, 0.f};
#pragma unroll
    for (int i = 0; i < 4; i++) {
      const int base = 4 * (lane + 64 * i);
      const float xe[4] = {v[i].x, v[i].y, v[i].z, v[i].w};
#pragma unroll
      for (int c = 0; c < 4; c++) {
        float4 wv = wa4[base + c];   // 16 KiB table, L1-hot
        p.x = fmaf(xe[c], wv.x, p.x);
        p.y = fmaf(xe[c], wv.y, p.y);
        p.z = fmaf(xe[c], wv.z, p.z);
        p.w = fmaf(xe[c], wv.w, p.w);
      }
      ushort4 hb;
      hb.x = f2bf(v[i].x); hb.y = f2bf(v[i].y);
      hb.z = f2bf(v[i].z); hb.w = f2bf(v[i].w);
      reinterpret_cast<ushort4*>(x_bf + (size_t)row * D_)[lane + 64 * i] = hb;
    }
    // in-wave butterfly reduce (no LDS, no barrier)
#pragma unroll
    for (int off = 32; off > 0; off >>= 1) {
      p.x += __shfl_xor(p.x, off);
      p.y += __shfl_xor(p.y, off);
      p.z += __shfl_xor(p.z, off);
      p.w += __shfl_xor(p.w, off);
    }
    if (lane == 0) {
      float l0 = p.x + b_att[0], l1 = p.y + b_att[1];
      float l2 = p.z + b_att[2], l3 = p.w + b_att[3];
      float mx = fmaxf(fmaxf(l0, l1), fmaxf(l2, l3));
      float e0 = __expf(l0 - mx), e1 = __expf(l1 - mx);
      float e2 = __expf(l2 - mx), e3 = __expf(l3 - mx);
      float inv = __builtin_amdgcn_rcpf(e0 + e1 + e2 + e3);
      reinterpret_cast<float4*>(attn)[row] =
          make_float4(e0 * inv, e1 * inv, e2 * inv, e3 * inv);
    }
  } else {
    const int wid = bid - M_ / 4;
    const int t = threadIdx.x;
    const int tx = t & 31, ty = t >> 5;
    const int c0 = (wid & 31) * 32;   // U
    const int r0 = (wid >> 5) * 32;   // D
#pragma unroll
    for (int i = 0; i < 4; i++) {
      int r = ty + i * 8;
      tile[r][tx] = w[(size_t)(r0 + r) * U_ + c0 + tx];
    }
    __syncthreads();
#pragma unroll
    for (int i = 0; i < 4; i++) {
      int r = ty + i * 8;
      wt[(size_t)(c0 + r) * D_ + r0 + tx] = f2bf(tile[tx][r]);
    }
  }
}

// ---------------- kernel 2: bf16 MFMA GEMM (x_bf @ w_t^T) + fused fast-math epilogue
#define BM 128
#define BN 128
#define BK 64
#define NXB (U_ / BN)            // 8 column-blocks
#define NWG ((M_ / BM) * NXB)    // 1024 workgroups

__global__ __launch_bounds__(256, 4) void k_gemm_ep(
    const uint16_t* __restrict__ xbf, const uint16_t* __restrict__ wt,
    const float* __restrict__ bias, const float* __restrict__ wf,
    const float* __restrict__ bfb, const float* __restrict__ attn,
    float* __restrict__ out) {
  __shared__ uint16_t As[BM * BK];   // [row m][k], 8-elem chunks XOR-swizzled by row&7
  __shared__ uint16_t Bs[BN * BK];   // [col n][k], same swizzle

  const int t = threadIdx.x;
  const int wave = t >> 6, lane = t & 63;
  const int l16 = lane & 15, quad = lane >> 4;
  const int wm = wave >> 1, wn = wave & 1;

  // XCD-aware bijective swizzle: hardware h -> logical l, so the 8 column-blocks
  // sharing an A row-panel land on the SAME XCD's L2 (h%8 == XCD).
  // NWG = 1024 divisible by 8 -> simple chunked swizzle is bijective.
  const int h = blockIdx.y * NXB + blockIdx.x;
  const int l = (h & 7) * (NWG / 8) + (h >> 3);
  const int bx = l & (NXB - 1);
  const int by = l / NXB;
  const int m0 = by * BM;
  const int n0 = bx * BN;

  const uint16_t* aBase = xbf + (size_t)m0 * D_;
  const uint16_t* bBase = wt + (size_t)n0 * D_;

  f32x4 acc[4][4] = {};

  for (int k0 = 0; k0 < D_; k0 += BK) {
#pragma unroll
    for (int it = 0; it < 4; it++) {
      int c = t + it * 256;          // chunk id: per-wave lane-contiguous
      int r = c >> 3;                // tile row (m for A, n for B)
      int cs = c & 7;                // swizzled chunk slot
      int gc = cs ^ (r & 7);         // global chunk
      async_copy16(aBase + (size_t)r * D_ + k0 + gc * 8, (uint8_t*)As + c * 16);
      async_copy16(bBase + (size_t)r * D_ + k0 + gc * 8, (uint8_t*)Bs + c * 16);
    }
    __syncthreads();

#pragma unroll
    for (int ks = 0; ks < 2; ks++) {
      const int kcb = ks * 4;        // chunk base within row (kk/8)
      bf16x8 af[4], bfr[4];
#pragma unroll
      for (int i = 0; i < 4; i++) {
        int r = wm * 64 + i * 16 + l16;
        int cs = (kcb + quad) ^ (r & 7);
        af[i] = *reinterpret_cast<const bf16x8*>(&As[r * BK + cs * 8]);
      }
#pragma unroll
      for (int j = 0; j < 4; j++) {
        int n = wn * 64 + j * 16 + l16;
        int cs = (kcb + quad) ^ (n & 7);
        bfr[j] = *reinterpret_cast<const bf16x8*>(&Bs[n * BK + cs * 8]);
      }
#pragma unroll
      for (int i = 0; i < 4; i++)
#pragma unroll
        for (int j = 0; j < 4; j++)
          acc[i][j] = __builtin_amdgcn_mfma_f32_16x16x32_bf16(af[i], bfr[j], acc[i][j], 0, 0, 0);
    }
    __syncthreads();
  }

  // ---- fused epilogue: 4 activations (fast-math) + attention-weighted reduce
  float bu[4];
  float4 wf4[4], bf4[4];
#pragma unroll
  for (int j = 0; j < 4; j++) {
    int u = n0 + wn * 64 + j * 16 + l16;
    bu[j] = bias[u];
    wf4[j] = reinterpret_cast<const float4*>(wf)[u];
    bf4[j] = reinterpret_cast<const float4*>(bfb)[u];
  }
#pragma unroll
  for (int i = 0; i < 4; i++) {
#pragma unroll
    for (int r = 0; r < 4; r++) {
      int mg = m0 + wm * 64 + i * 16 + quad * 4 + r;   // C/D: row = quad*4+reg
      float4 at = reinterpret_cast<const float4*>(attn)[mg];
      float* orow = out + (size_t)mg * U_;
#pragma unroll
      for (int j = 0; j < 4; j++) {
        int u = n0 + wn * 64 + j * 16 + l16;            // C/D: col = lane&15
        float wsv = acc[i][j][r] + bu[j];
        float wa0 = fmaf(wsv, wf4[j].x, bf4[j].x);
        float wa1 = fmaf(wsv, wf4[j].y, bf4[j].y);
        float wa2 = fmaf(wsv, wf4[j].z, bf4[j].z);
        float wa3 = fmaf(wsv, wf4[j].w, bf4[j].w);
        // relu
        float a_relu = fmaxf(wa0, 0.f);
        // sigmoid(x) = rcp(1 + 2^(-log2e*x))
        float a_sig = __builtin_amdgcn_rcpf(
            1.f + __builtin_amdgcn_exp2f(-1.4426950409f * wa1));
        // tanh(x) = 2*sigmoid(2x) - 1
        float a_tanh = fmaf(2.f, __builtin_amdgcn_rcpf(
            1.f + __builtin_amdgcn_exp2f(-2.8853900818f * wa2)), -1.f);
        // gelu(x) ~= x * sigmoid(2*0.7978845608*(x + 0.044715 x^3))
        float y = wa3 * fmaf(0.044715f, wa3 * wa3, 1.f);
        float a_gelu = wa3 * __builtin_amdgcn_rcpf(
            1.f + __builtin_amdgcn_exp2f(-2.302207929f * y));
        float res = at.x * a_relu + at.y * a_sig + at.z * a_tanh + at.w * a_gelu;
        // write-once stream: keep it out of L2 so A/B panels stay resident
        __builtin_nontemporal_store(res, &orow[u]);
      }
    }
  }
}

extern "C" void kernel_launch(void* const* d_in, const int* in_sizes, int n_in,
                              void* d_out, int out_size, void* d_ws, size_t ws_size,
                              hipStream_t stream) {
  const float* x     = (const float*)d_in[0];
  const float* w     = (const float*)d_in[1];
  const float* b     = (const float*)d_in[2];
  const float* wf    = (const float*)d_in[3];
  const float* bfb   = (const float*)d_in[4];
  const float* w_att = (const float*)d_in[5];
  const float* b_att = (const float*)d_in[6];
  float* out = (float*)d_out;

  char* ws = (char*)d_ws;
  uint16_t* x_bf = (uint16_t*)ws;                          // 32 MiB
  uint16_t* w_t  = (uint16_t*)(ws + ((size_t)32 << 20));   // 2 MiB
  float*    attn = (float*)(ws + ((size_t)34 << 20));      // 256 KiB

  k_prep<<<dim3(M_ / 4 + 1024), 256, 0, stream>>>(x, w_att, b_att, w, x_bf, attn, w_t);
  k_gemm_ep<<<dim3(U_ / BN, M_ / BM), 256, 0, stream>>>(x_bf, w_t, b, wf, bfb, attn, out);
}

// Round 3
// 173.530 us; speedup vs baseline: 1.0341x; 1.0018x over previous
//
#include <hip/hip_runtime.h>
#include <hip/hip_bf16.h>
#include <cstdint>

#define B_ 8
#define S_ 2048
#define D_ 1024
#define U_ 1024
#define M_ (B_ * S_)   // 16384 rows

typedef __bf16 bf16x8 __attribute__((ext_vector_type(8)));
typedef float  f32x4  __attribute__((ext_vector_type(4)));

__device__ __forceinline__ uint16_t f2bf(float f) {
  uint32_t u = __builtin_bit_cast(uint32_t, f);
  u += 0x7fffu + ((u >> 16) & 1u);   // RNE
  return (uint16_t)(u >> 16);
}

// async 16B global->LDS copy (lane-contiguous LDS destination)
__device__ __forceinline__ void async_copy16(const void* g, void* l) {
  typedef const __attribute__((address_space(1))) uint8_t* gp_t;
  typedef __attribute__((address_space(3))) uint8_t* lp_t;
  __builtin_amdgcn_global_load_lds((gp_t)(uintptr_t)g,
                                   (lp_t)(uint32_t)(uintptr_t)l, 16, 0, 0);
}

// ---------------- kernel 1 (fused prep):
//   blocks [0, M_/4):      wave-per-row: x -> x_bf (bf16) + attn softmax (no barriers)
//   blocks [M_/4, +1024):  w [D][U] f32 -> wt [U][D] bf16 (LDS tile transpose)
__global__ __launch_bounds__(256) void k_prep(
    const float* __restrict__ x, const float* __restrict__ w_att,
    const float* __restrict__ b_att, const float* __restrict__ w,
    uint16_t* __restrict__ x_bf, float* __restrict__ attn,
    uint16_t* __restrict__ wt) {
  __shared__ float tile[32][33];     // used only by transpose blocks
  const int bid = blockIdx.x;
  if (bid < M_ / 4) {
    const int wave = threadIdx.x >> 6, lane = threadIdx.x & 63;
    const int row = bid * 4 + wave;
    const float4* xr = reinterpret_cast<const float4*>(x + (size_t)row * D_);
    const float4* wa4 = reinterpret_cast<const float4*>(w_att);
    float4 v[4];
#pragma unroll
    for (int i = 0; i < 4; i++) v[i] = xr[lane + 64 * i];   // 16 B/lane coalesced
    float4 p = {0.f, 0.f, 0.f, 0.f};
#pragma unroll
    for (int i = 0; i < 4; i++) {
      const int base = 4 * (lane + 64 * i);
      const float xe[4] = {v[i].x, v[i].y, v[i].z, v[i].w};
#pragma unroll
      for (int c = 0; c < 4; c++) {
        float4 wv = wa4[base + c];   // 16 KiB table, L1-hot
        p.x = fmaf(xe[c], wv.x, p.x);
        p.y = fmaf(xe[c], wv.y, p.y);
        p.z = fmaf(xe[c], wv.z, p.z);
        p.w = fmaf(xe[c], wv.w, p.w);
      }
      ushort4 hb;
      hb.x = f2bf(v[i].x); hb.y = f2bf(v[i].y);
      hb.z = f2bf(v[i].z); hb.w = f2bf(v[i].w);
      reinterpret_cast<ushort4*>(x_bf + (size_t)row * D_)[lane + 64 * i] = hb;
    }
    // in-wave butterfly reduce (no LDS, no barrier)
#pragma unroll
    for (int off = 32; off > 0; off >>= 1) {
      p.x += __shfl_xor(p.x, off);
      p.y += __shfl_xor(p.y, off);
      p.z += __shfl_xor(p.z, off);
      p.w += __shfl_xor(p.w, off);
    }
    if (lane == 0) {
      float l0 = p.x + b_att[0], l1 = p.y + b_att[1];
      float l2 = p.z + b_att[2], l3 = p.w + b_att[3];
      float mx = fmaxf(fmaxf(l0, l1), fmaxf(l2, l3));
      float e0 = __expf(l0 - mx), e1 = __expf(l1 - mx);
      float e2 = __expf(l2 - mx), e3 = __expf(l3 - mx);
      float inv = __builtin_amdgcn_rcpf(e0 + e1 + e2 + e3);
      reinterpret_cast<float4*>(attn)[row] =
          make_float4(e0 * inv, e1 * inv, e2 * inv, e3 * inv);
    }
  } else {
    const int wid = bid - M_ / 4;
    const int t = threadIdx.x;
    const int tx = t & 31, ty = t >> 5;
    const int c0 = (wid & 31) * 32;   // U
    const int r0 = (wid >> 5) * 32;   // D
#pragma unroll
    for (int i = 0; i < 4; i++) {
      int r = ty + i * 8;
      tile[r][tx] = w[(size_t)(r0 + r) * U_ + c0 + tx];
    }
    __syncthreads();
#pragma unroll
    for (int i = 0; i < 4; i++) {
      int r = ty + i * 8;
      wt[(size_t)(c0 + r) * D_ + r0 + tx] = f2bf(tile[tx][r]);
    }
  }
}

// ---------------- kernel 2: 256x256-tile 8-phase bf16 MFMA GEMM + fused epilogue
// 512 threads = 8 waves (2M x 4N per quadrant), BK=64, double-buffered LDS (128 KiB).
// Race-free stage schedule: a half-tile is staged only in a phase AFTER its last
// read (WAR safe via barrier+lgkmcnt), and vmcnt(4) at ph4/ph8 proves (in-order
// VMEM retirement) that the next-consumed buffer has fully landed (RAW safe).
#define BM 256
#define BN 256
#define BK 64
#define NKT (D_ / BK)            // 16 K-tiles

__global__ __launch_bounds__(512, 2) void k_gemm_ep(
    const uint16_t* __restrict__ xbf, const uint16_t* __restrict__ wt,
    const float* __restrict__ bias, const float* __restrict__ wf,
    const float* __restrict__ bfb, const float* __restrict__ attn,
    float* __restrict__ out) {
  __shared__ uint16_t As[2][BM * BK];   // [buf][row m][k], chunk-swizzled by row&7
  __shared__ uint16_t Bs[2][BN * BK];   // [buf][col n][k], same swizzle

  const int t = threadIdx.x;
  const int lane = t & 63;
  const int wave = t >> 6;
  const int l16 = lane & 15, quad = lane >> 4;
  const int wm = wave >> 2;   // 0..1  (64-row slice within a 128-row half)
  const int wn = wave & 3;    // 0..3  (32-col slice within a 128-col half)

  // XCD-aware bijective swizzle (grid = 4 x 64 = 256 = 8 XCDs x 32)
  const int h = blockIdx.y * (U_ / BN) + blockIdx.x;
  const int l = (h & 7) * 32 + (h >> 3);
  const int bx = l & 3;
  const int by = l >> 2;
  const int m0 = by * BM;
  const int n0 = bx * BN;

  const uint16_t* aBase = xbf + (size_t)m0 * D_;
  const uint16_t* bBase = wt + (size_t)n0 * D_;

  f32x4 acc[2][2][4][2] = {};   // [MH][NH][i][j] -- always statically indexed

  // stage one 16-KiB half-tile (128 rows x 64 k, bf16): 512 thr x 2 x 16 B
#define STAGE_A(BF, H, KS) do {                                              \
    const uint16_t* _g = aBase + (size_t)((H) * 128) * D_ + (KS) * BK;       \
    uint8_t* _l = (uint8_t*)As + (BF) * (BM * BK * 2) + (H) * 128 * BK * 2;  \
    int _c0 = t;                                                             \
    async_copy16(_g + (size_t)(_c0 >> 3) * D_ + ((_c0 & 7) ^ ((_c0 >> 3) & 7)) * 8, \
                 _l + _c0 * 16);                                             \
    int _c1 = t + 512;                                                       \
    async_copy16(_g + (size_t)(_c1 >> 3) * D_ + ((_c1 & 7) ^ ((_c1 >> 3) & 7)) * 8, \
                 _l + _c1 * 16);                                             \
  } while (0)

#define STAGE_B(BF, H, KS) do {                                              \
    const uint16_t* _g = bBase + (size_t)((H) * 128) * D_ + (KS) * BK;       \
    uint8_t* _l = (uint8_t*)Bs + (BF) * (BN * BK * 2) + (H) * 128 * BK * 2;  \
    int _c0 = t;                                                             \
    async_copy16(_g + (size_t)(_c0 >> 3) * D_ + ((_c0 & 7) ^ ((_c0 >> 3) & 7)) * 8, \
                 _l + _c0 * 16);                                             \
    int _c1 = t + 512;                                                       \
    async_copy16(_g + (size_t)(_c1 >> 3) * D_ + ((_c1 & 7) ^ ((_c1 >> 3) & 7)) * 8, \
                 _l + _c1 * 16);                                             \
  } while (0)

  // vmcnt(4): with in-order VMEM retirement, all but the newest 2 stages
  // (2 loads each) have landed -> the buffer consumed next is complete.
#define VM4 asm volatile("s_waitcnt vmcnt(4)" ::: "memory")
#define NOWAIT

  // one phase: 12 ds_read_b128 || stage 1 half-tile -> barrier -> 16 MFMA
#define PHASE(BF, MH, NH, STAGE, WAIT) do {                                  \
    __builtin_amdgcn_sched_barrier(0);  /* pin phase start */                \
    bf16x8 _a[4][2], _b[2][2];                                               \
    _Pragma("unroll")                                                        \
    for (int i = 0; i < 4; i++) {                                            \
      int r = (MH) * 128 + wm * 64 + i * 16 + l16;                           \
      _Pragma("unroll")                                                      \
      for (int kh = 0; kh < 2; kh++) {                                       \
        int cs = (kh * 4 + quad) ^ (r & 7);                                  \
        _a[i][kh] = *reinterpret_cast<const bf16x8*>(&As[BF][r * BK + cs * 8]); \
      }                                                                      \
    }                                                                        \
    _Pragma("unroll")                                                        \
    for (int j = 0; j < 2; j++) {                                            \
      int n = (NH) * 128 + wn * 32 + j * 16 + l16;                           \
      _Pragma("unroll")                                                      \
      for (int kh = 0; kh < 2; kh++) {                                       \
        int cs = (kh * 4 + quad) ^ (n & 7);                                  \
        _b[j][kh] = *reinterpret_cast<const bf16x8*>(&Bs[BF][n * BK + cs * 8]); \
      }                                                                      \
    }                                                                        \
    STAGE;                                                                   \
    __builtin_amdgcn_sched_barrier(0);  /* reads+stage stay before barrier */\
    __builtin_amdgcn_s_barrier();                                            \
    asm volatile("s_waitcnt lgkmcnt(0)" ::: "memory");                       \
    __builtin_amdgcn_sched_barrier(0);  /* rule 18: no MFMA hoist */         \
    __builtin_amdgcn_s_setprio(1);                                           \
    _Pragma("unroll")                                                        \
    for (int kh = 0; kh < 2; kh++)                                           \
      _Pragma("unroll")                                                      \
      for (int i = 0; i < 4; i++)                                            \
        _Pragma("unroll")                                                    \
        for (int j = 0; j < 2; j++)                                          \
          acc[MH][NH][i][j] = __builtin_amdgcn_mfma_f32_16x16x32_bf16(       \
              _a[i][kh], _b[j][kh], acc[MH][NH][i][j], 0, 0, 0);             \
    __builtin_amdgcn_s_setprio(0);                                           \
    WAIT;                                                                    \
    __builtin_amdgcn_s_barrier();                                            \
  } while (0)

  // ---- prologue: tile0 -> buf0 (4 halves), tile1.A0/B0 -> buf1
  STAGE_A(0, 0, 0); STAGE_B(0, 0, 0); STAGE_A(0, 1, 0); STAGE_B(0, 1, 0);
  STAGE_A(1, 0, 1); STAGE_B(1, 0, 1);
  asm volatile("s_waitcnt vmcnt(4)" ::: "memory");   // buf0 landed; 2 stages in flight
  __builtin_amdgcn_s_barrier();

  // ---- main loop: 8 iterations x 2 K-tiles (buf0 = tile 2it, buf1 = 2it+1)
  // Reads per phase:  ph1 A0B0(buf0) ph2 A0B1 ph3 A1B0 ph4 A1B1
  //                   ph5 A0B0(buf1) ph6 A0B1 ph7 A1B0 ph8 A1B1
  // Stages (each issued the phase AFTER the target half's last read):
  //   ph1 buf1.B1<-t(2it+1)  ph2 buf1.A1<-t(2it+1)
  //   ph3 buf0.A0<-t(2it+2)  ph4 buf0.B0 [VM4: buf1 complete]
  //   ph5 buf0.A1            ph6 buf0.B1
  //   ph7 buf1.A0<-t(2it+3)  ph8 buf1.B0 [VM4: buf0 complete]
  for (int it = 0; it < 8; ++it) {
    const int t1k = 2 * it + 1;
    const int s0 = (2 * it + 2 < NKT) ? 2 * it + 2 : NKT - 1;   // clamped stages are
    const int s1 = (2 * it + 3 < NKT) ? 2 * it + 3 : NKT - 1;   // never consumed

    PHASE(0, 0, 0, STAGE_B(1, 1, t1k), NOWAIT);
    PHASE(0, 0, 1, STAGE_A(1, 1, t1k), NOWAIT);
    PHASE(0, 1, 0, STAGE_A(0, 0, s0),  NOWAIT);
    PHASE(0, 1, 1, STAGE_B(0, 0, s0),  VM4);     // buf1 (tile 2it+1) fully landed
    PHASE(1, 0, 0, STAGE_A(0, 1, s0),  NOWAIT);
    PHASE(1, 0, 1, STAGE_B(0, 1, s0),  NOWAIT);
    PHASE(1, 1, 0, STAGE_A(1, 0, s1),  NOWAIT);
    PHASE(1, 1, 1, STAGE_B(1, 0, s1),  VM4);     // buf0 (tile 2it+2) fully landed
  }

  // ---- fused epilogue: 4 activations (fast-math) + attention-weighted reduce
  float  bu[2][2];
  float4 wfv[2][2], bfv[2][2];
#pragma unroll
  for (int NH = 0; NH < 2; NH++)
#pragma unroll
    for (int j = 0; j < 2; j++) {
      int u = n0 + NH * 128 + wn * 32 + j * 16 + l16;
      bu[NH][j]  = bias[u];
      wfv[NH][j] = reinterpret_cast<const float4*>(wf)[u];
      bfv[NH][j] = reinterpret_cast<const float4*>(bfb)[u];
    }
#pragma unroll
  for (int MH = 0; MH < 2; MH++) {
#pragma unroll
    for (int i = 0; i < 4; i++) {
#pragma unroll
      for (int r = 0; r < 4; r++) {
        int mg = m0 + MH * 128 + wm * 64 + i * 16 + quad * 4 + r;  // C/D: row=quad*4+reg
        float4 at = reinterpret_cast<const float4*>(attn)[mg];
        float* orow = out + (size_t)mg * U_;
#pragma unroll
        for (int NH = 0; NH < 2; NH++) {
#pragma unroll
          for (int j = 0; j < 2; j++) {
            int u = n0 + NH * 128 + wn * 32 + j * 16 + l16;        // C/D: col=lane&15
            float wsv = acc[MH][NH][i][j][r] + bu[NH][j];
            float wa0 = fmaf(wsv, wfv[NH][j].x, bfv[NH][j].x);
            float wa1 = fmaf(wsv, wfv[NH][j].y, bfv[NH][j].y);
            float wa2 = fmaf(wsv, wfv[NH][j].z, bfv[NH][j].z);
            float wa3 = fmaf(wsv, wfv[NH][j].w, bfv[NH][j].w);
            float a_relu = fmaxf(wa0, 0.f);
            float a_sig = __builtin_amdgcn_rcpf(
                1.f + __builtin_amdgcn_exp2f(-1.4426950409f * wa1));
            float a_tanh = fmaf(2.f, __builtin_amdgcn_rcpf(
                1.f + __builtin_amdgcn_exp2f(-2.8853900818f * wa2)), -1.f);
            float y = wa3 * fmaf(0.044715f, wa3 * wa3, 1.f);
            float a_gelu = wa3 * __builtin_amdgcn_rcpf(
                1.f + __builtin_amdgcn_exp2f(-2.302207929f * y));
            orow[u] = at.x * a_relu + at.y * a_sig + at.z * a_tanh + at.w * a_gelu;
          }
        }
      }
    }
  }
}

extern "C" void kernel_launch(void* const* d_in, const int* in_sizes, int n_in,
                              void* d_out, int out_size, void* d_ws, size_t ws_size,
                              hipStream_t stream) {
  const float* x     = (const float*)d_in[0];
  const float* w     = (const float*)d_in[1];
  const float* b     = (const float*)d_in[2];
  const float* wf    = (const float*)d_in[3];
  const float* bfb   = (const float*)d_in[4];
  const float* w_att = (const float*)d_in[5];
  const float* b_att = (const float*)d_in[6];
  float* out = (float*)d_out;

  char* ws = (char*)d_ws;
  uint16_t* x_bf = (uint16_t*)ws;                          // 32 MiB
  uint16_t* w_t  = (uint16_t*)(ws + ((size_t)32 << 20));   // 2 MiB
  float*    attn = (float*)(ws + ((size_t)34 << 20));      // 256 KiB

  k_prep<<<dim3(M_ / 4 + 1024), 256, 0, stream>>>(x, w_att, b_att, w, x_bf, attn, w_t);
  k_gemm_ep<<<dim3(U_ / BN, M_ / BM), 512, 0, stream>>>(x_bf, w_t, b, wf, bfb, attn, out);
}